// Round 2
// baseline (882.406 us; speedup 1.0000x reference)
//
#include <hip/hip_runtime.h>
#include <stdint.h>

typedef short bf8 __attribute__((ext_vector_type(8)));   // 8 bf16 (4 VGPRs)
typedef float f4  __attribute__((ext_vector_type(4)));   // MFMA acc
typedef unsigned short u16;

#define LOG2E 1.4426950408889634f

// float -> bf16 (RNE)
__device__ __forceinline__ u16 f2bf(float f){
  uint32_t u = __builtin_bit_cast(uint32_t, f);
  u += 0x7fffu + ((u >> 16) & 1u);
  return (u16)(u >> 16);
}
// sigmoid of a value pre-scaled by log2(e):  1/(1+2^-a)
__device__ __forceinline__ float sigm_ps(float a){
  return __builtin_amdgcn_rcpf(1.0f + __builtin_amdgcn_exp2f(-a));
}

// ---------------------------------------------------------------------------
// Prep: build prescaled bf16 concatenated weights  W0c[512][160] = [Whh0|Wih0|0],
// W1c[512][256] = [Whh1|Wih1], rows scaled by log2e (i,f,o) / 2*log2e (g gate),
// and combined prescaled biases.
// ---------------------------------------------------------------------------
__global__ void prep_kernel(const float* __restrict__ Wih0, const float* __restrict__ Whh0,
                            const float* __restrict__ bih0, const float* __restrict__ bhh0,
                            const float* __restrict__ Wih1, const float* __restrict__ Whh1,
                            const float* __restrict__ bih1, const float* __restrict__ bhh1,
                            u16* __restrict__ W0c, u16* __restrict__ W1c,
                            float* __restrict__ bias0, float* __restrict__ bias1){
  int g = blockIdx.x;      // gate row 0..511
  int t = threadIdx.x;     // 0..63
  float s = (g >= 256 && g < 384) ? 2.0f * LOG2E : LOG2E;   // g-gate rows get 2*log2e
  for(int k = t; k < 160; k += 64){
    float v = 0.0f;
    if(k < 128)      v = Whh0[g*128 + k];
    else if(k < 146) v = Wih0[g*18 + (k-128)];
    W0c[g*160 + k] = f2bf(v * s);
  }
  for(int k = t; k < 256; k += 64){
    float v = (k < 128) ? Whh1[g*128 + k] : Wih1[g*128 + (k-128)];
    W1c[g*256 + k] = f2bf(v * s);
  }
  if(t == 0){
    bias0[g] = (bih0[g] + bhh0[g]) * s;
    bias1[g] = (bih1[g] + bhh1[g]) * s;
  }
}

// ---------------------------------------------------------------------------
// Persistent LSTM layer. 256 blocks x 512 threads; block owns batch rows
// {2*bid, 2*bid+1} for all 512 timesteps. K-concatenated MFMA:
//   L0: A=[h(128)|x_t(18)|0pad]  K=160 (KT=5)
//   L1: A=[h2(128)|h1_t(128)]    K=256 (KT=8)
// Wave w covers gate columns q*128 + [16w,16w+16) for q=0..3 (B frags in VGPRs).
// ---------------------------------------------------------------------------
template<int KT, int RS, bool IS_L0>
__global__ __launch_bounds__(512)
void lstm_kernel(const u16* __restrict__ Wc, const float* __restrict__ bias,
                 const float* __restrict__ xin,        // L0 input (B,T,18) f32
                 const u16*   __restrict__ h1in,       // L1 input (B,T,128) bf16
                 u16*         __restrict__ h1out,      // L0 output (B,T,128) bf16
                 const float* __restrict__ Wfc1, const float* __restrict__ bfc1,
                 const float* __restrict__ Wfc2, const float* __restrict__ bfc2,
                 float* __restrict__ out)              // L1 only: (512,) f32
{
  constexpr int K = KT * 32;
  __shared__ __align__(16) u16  Abuf[2 * RS];   // 2 rows x (K + pad)
  __shared__ __align__(16) float gbuf[1024];    // raw gates [col][m] (float2 per col)

  const int tid  = threadIdx.x;
  const int wave = tid >> 6;
  const int lane = tid & 63;
  const int quad = lane >> 4;
  const int l15  = lane & 15;
  const int bid  = blockIdx.x;

  // ---- persistent B fragments: lane holds B[k=quad*8+j][n=l15] = Wc[n][k]
  bf8 Bf[4][KT];
#pragma unroll
  for(int q = 0; q < 4; q++){
    int n = q*128 + 16*wave + l15;
#pragma unroll
    for(int kt = 0; kt < KT; kt++){
      Bf[q][kt] = *(const bf8*)(Wc + n*K + kt*32 + quad*8);
    }
  }

  // update-thread mapping (tid<256): row um, component uj
  const int um = tid >> 7;
  const int uj = tid & 127;
  float b4[4] = {0.f,0.f,0.f,0.f};
  if(tid < 256){
#pragma unroll
    for(int q = 0; q < 4; q++) b4[q] = bias[q*128 + uj];
  }
  float cst = 0.0f, hreg = 0.0f;

  // ---- init A buffer: zero everything, then stage t=0 input
  for(int k2 = tid; k2 < 2*RS; k2 += 512) Abuf[k2] = 0;
  __syncthreads();
  if(IS_L0){
    if(tid >= 256 && tid < 292){
      int u = tid - 256, m = u / 18, kk = u - 18*m;
      Abuf[m*RS + 128 + kk] = f2bf(xin[((2*bid + m)*512)*18 + kk]);
    }
  } else {
    if(tid >= 256 && tid < 288){
      int u = tid - 256, m = u >> 4, ch = u & 15;
      *(uint4*)(Abuf + m*RS + 128 + ch*8) =
          *(const uint4*)(h1in + ((2*bid + m)*512)*128 + ch*8);
    }
  }
  __syncthreads();

  for(int t = 0; t < 512; t++){
    // ---- prefetch t+1 inputs into registers (latency hides under MFMA)
    float xv = 0.0f; uint4 pv = {0u,0u,0u,0u};
    if(IS_L0){
      if(tid >= 256 && tid < 292 && t < 511){
        int u = tid - 256, m = u / 18, kk = u - 18*m;
        xv = xin[((2*bid + m)*512 + t + 1)*18 + kk];
      }
    } else {
      if(tid >= 256 && tid < 288 && t < 511){
        int u = tid - 256, m = u >> 4, ch = u & 15;
        pv = *(const uint4*)(h1in + ((2*bid + m)*512 + t + 1)*128 + ch*8);
      }
    }

    // ---- A fragments: lane (m=l15) reads row (m&1); m>=2 gets harmless dup data
    bf8 Af[KT];
    {
      const u16* ar = Abuf + (l15 & 1)*RS + quad*8;
#pragma unroll
      for(int kt = 0; kt < KT; kt++) Af[kt] = *(const bf8*)(ar + kt*32);
    }

    // ---- MFMA: 4 independent acc chains (one per gate group)
    f4 acc[4];
#pragma unroll
    for(int q = 0; q < 4; q++){ f4 z = {0.f,0.f,0.f,0.f}; acc[q] = z; }
#pragma unroll
    for(int kt = 0; kt < KT; kt++){
#pragma unroll
      for(int q = 0; q < 4; q++){
        acc[q] = __builtin_amdgcn_mfma_f32_16x16x32_bf16(Af[kt], Bf[q][kt], acc[q], 0, 0, 0);
      }
    }

    // ---- export raw gates: D rows 0,1 live in quad0 regs 0,1 (lanes 0-15)
    if(lane < 16){
#pragma unroll
      for(int q = 0; q < 4; q++){
        int col = q*128 + 16*wave + lane;
        *(float2*)(gbuf + 2*col) = make_float2(acc[q][0], acc[q][1]);
      }
    }
    __syncthreads();

    // ---- pointwise cell update (fp32 state), threads 0-255
    if(tid < 256){
      float a0 = gbuf[2*(uj      ) + um] + b4[0];
      float a1 = gbuf[2*(uj + 128) + um] + b4[1];
      float a2 = gbuf[2*(uj + 256) + um] + b4[2];
      float a3 = gbuf[2*(uj + 384) + um] + b4[3];
      float ig = sigm_ps(a0);
      float fg = sigm_ps(a1);
      float gg = 2.0f * sigm_ps(a2) - 1.0f;        // tanh via 2*sigma(2x)-1 (prescaled)
      float og = sigm_ps(a3);
      cst = fg*cst + ig*gg;
      float th = 2.0f * sigm_ps(cst * (2.0f * LOG2E)) - 1.0f;
      hreg = og * th;
      u16 hb = f2bf(hreg);
      Abuf[um*RS + uj] = hb;                        // next-step state
      if(IS_L0) h1out[((2*bid + um)*512 + t)*128 + uj] = hb;
    } else {
      // ---- stage prefetched t+1 input into A buffer
      if(IS_L0){
        if(tid < 292 && t < 511){
          int u = tid - 256, m = u / 18, kk = u - 18*m;
          Abuf[m*RS + 128 + kk] = f2bf(xv);
        }
      } else {
        if(tid < 288 && t < 511){
          int u = tid - 256, m = u >> 4, ch = u & 15;
          *(uint4*)(Abuf + m*RS + 128 + ch*8) = pv;
        }
      }
    }
    __syncthreads();
  }

  // ---- fused FC head (L1 only), fp32
  if(!IS_L0){
    if(tid < 256) gbuf[um*128 + uj] = hreg;
    __syncthreads();
    if(tid < 128){
      int m = tid >> 6, v = tid & 63;
      float s = bfc1[v];
      for(int j = 0; j < 128; j++) s = fmaf(Wfc1[v*128 + j], gbuf[m*128 + j], s);
      s = fmaxf(s, 0.0f);
      float term = s * Wfc2[v];
#pragma unroll
      for(int off = 32; off > 0; off >>= 1) term += __shfl_down(term, off);
      if(v == 0){
        out[2*bid + m] = sigm_ps((term + bfc2[0]) * LOG2E);
      }
    }
  }
}

// ---------------------------------------------------------------------------
extern "C" void kernel_launch(void* const* d_in, const int* in_sizes, int n_in,
                              void* d_out, int out_size, void* d_ws, size_t ws_size,
                              hipStream_t stream){
  const float* x    = (const float*)d_in[0];
  const float* Wih0 = (const float*)d_in[1];
  const float* Whh0 = (const float*)d_in[2];
  const float* bih0 = (const float*)d_in[3];
  const float* bhh0 = (const float*)d_in[4];
  const float* Wih1 = (const float*)d_in[5];
  const float* Whh1 = (const float*)d_in[6];
  const float* bih1 = (const float*)d_in[7];
  const float* bhh1 = (const float*)d_in[8];
  const float* Wfc1 = (const float*)d_in[9];
  const float* bfc1 = (const float*)d_in[10];
  const float* Wfc2 = (const float*)d_in[11];
  const float* bfc2 = (const float*)d_in[12];

  char* ws = (char*)d_ws;
  u16*   W0c   = (u16*)(ws);                       // 512*160*2 = 163840 B
  u16*   W1c   = (u16*)(ws + 163840);              // 512*256*2 = 262144 B
  float* bias0 = (float*)(ws + 163840 + 262144);   // 2048 B
  float* bias1 = bias0 + 512;                      // 2048 B
  u16*   h1    = (u16*)(ws + 163840 + 262144 + 4096);  // 512*512*128*2 = 64 MiB

  prep_kernel<<<dim3(512), dim3(64), 0, stream>>>(Wih0, Whh0, bih0, bhh0,
                                                  Wih1, Whh1, bih1, bhh1,
                                                  W0c, W1c, bias0, bias1);

  // Layer 0: K = 160 (KT=5), row stride 168 (+8 pad)
  lstm_kernel<5, 168, true><<<dim3(256), dim3(512), 0, stream>>>(
      W0c, bias0, x, nullptr, h1,
      nullptr, nullptr, nullptr, nullptr, nullptr);

  // Layer 1: K = 256 (KT=8), row stride 264 (+8 pad); fused FC head
  lstm_kernel<8, 264, false><<<dim3(256), dim3(512), 0, stream>>>(
      W1c, bias1, nullptr, h1, nullptr,
      Wfc1, bfc1, Wfc2, bfc2, (float*)d_out);
}